// Round 2
// baseline (189.818 us; speedup 1.0000x reference)
//
#include <hip/hip_runtime.h>
#include <hip/hip_bf16.h>

typedef __attribute__((ext_vector_type(8))) short bf16x8;
typedef __attribute__((ext_vector_type(4))) float f32x4;

#define FSW(c) (((c) >> 1) & 3)

static __device__ __forceinline__ uint bf16rne(float f) {
    uint u = __float_as_uint(f);
    return (u + 0x7fffu + ((u >> 16) & 1u)) >> 16;
}

// K1: style_plus1[b][c] = 1 + affine_b[c] + dot(w[b,:], affine_w[c,:])
__global__ void k_style(const float* __restrict__ w, const float* __restrict__ aw,
                        const float* __restrict__ ab, float* __restrict__ style) {
    int idx = blockIdx.x * 4 + (threadIdx.x >> 6);
    int lane = threadIdx.x & 63;
    int b = idx >> 9, c = idx & 511;
    const float* wp = w + b * 512;
    const float* ap = aw + (size_t)c * 512;
    float s = 0.f;
    #pragma unroll
    for (int i = 0; i < 8; ++i) s += wp[lane + i * 64] * ap[lane + i * 64];
    #pragma unroll
    for (int m = 32; m; m >>= 1) s += __shfl_xor(s, m, 64);
    if (lane == 0) style[idx] = s + ab[c] + 1.0f;
}

// K2: Wf[grp16][chunk16][tap9][fm2][lane64][8] = bf16 weight in MFMA A-frag order
//     wsq[o][c] = sum_tap w^2
__global__ void k_wprep(const float* __restrict__ weight, ushort* __restrict__ Wf,
                        float* __restrict__ wsq) {
    int t = blockIdx.x * 256 + threadIdx.x;          // (o,c)
    int o = t >> 9, c = t & 511;
    int grp = o >> 5, rr = o & 31, fm = rr >> 4, l15r = rr & 15;
    int chunkid = c >> 5, kgw = (c >> 3) & 3, kk = c & 7;
    int lanew = kgw * 16 + l15r;
    const float* wp = weight + (size_t)t * 9;
    size_t G = (size_t)(grp * 16 + chunkid);
    size_t base = G * 9216 + (size_t)fm * 512 + (size_t)lanew * 8 + kk;
    float sq = 0.f;
    #pragma unroll
    for (int j = 0; j < 9; ++j) {
        float v = wp[j];
        sq += v * v;
        Wf[base + (size_t)j * 1024] = (ushort)bf16rne(v);
    }
    wsq[t] = sq;
}

// K3: sigma[b][o] = rsqrt( sum_c style^2[b,c] * wsq[o,c] + eps )
__global__ void k_sigma(const float* __restrict__ style, const float* __restrict__ wsq,
                        float* __restrict__ sigma) {
    int idx = blockIdx.x * 4 + (threadIdx.x >> 6);
    int lane = threadIdx.x & 63;
    int b = idx >> 9, o = idx & 511;
    const float* sp = style + b * 512;
    const float* qp = wsq + (size_t)o * 512;
    float s = 0.f;
    #pragma unroll
    for (int i = 0; i < 8; ++i) {
        float st = sp[lane + i * 64];
        s += st * st * qp[lane + i * 64];
    }
    #pragma unroll
    for (int m = 32; m; m >>= 1) s += __shfl_xor(s, m, 64);
    if (lane == 0) sigma[idx] = rsqrtf(s + 1e-8f);
}

// K_premod: xb[b][y][x][c] = bf16( x[b][c][y][x] * style[b][c] )   (NHWC)
__global__ void k_premod(const float* __restrict__ x, const float* __restrict__ style,
                         ushort* __restrict__ xb) {
    int bid = blockIdx.x;            // b*64 + y
    int b = bid >> 6, y = bid & 63;
    int xcol = threadIdx.x >> 2, cg = threadIdx.x & 3;
    const float* sp = style + b * 512;
    #pragma unroll 1
    for (int cb = 0; cb < 16; ++cb) {
        int c0 = cb * 32 + cg * 8;
        float v[8];
        #pragma unroll
        for (int j = 0; j < 8; ++j)
            v[j] = x[((size_t)(b * 512 + c0 + j) * 64 + y) * 64 + xcol] * sp[c0 + j];
        uint4 pk;
        pk.x = bf16rne(v[0]) | (bf16rne(v[1]) << 16);
        pk.y = bf16rne(v[2]) | (bf16rne(v[3]) << 16);
        pk.z = bf16rne(v[4]) | (bf16rne(v[5]) << 16);
        pk.w = bf16rne(v[6]) | (bf16rne(v[7]) << 16);
        *(uint4*)&xb[((size_t)(b * 64 + y) * 64 + xcol) * 512 + c0] = pk;
    }
}

// K4: implicit-GEMM conv. Block: 128 o x 128 px (2 rows). Wave: 32 o x 128 px.
// A fragments global->VGPR (L2), x-tile LDS double-buffered, 1 barrier/chunk.
__global__ __launch_bounds__(256, 3) void k_conv(
    const ushort* __restrict__ xb, const ushort* __restrict__ Wf,
    const float* __restrict__ sigma, const float* __restrict__ bias,
    float* __restrict__ out) {

    __shared__ ushort sX[2][4 * 66 * 32];   // [buf][row][col][32ch], swizzled 16B slots

    const int tid = threadIdx.x, bid = blockIdx.x;
    const int ob = bid & 3, pb = bid >> 2;
    const int b = pb >> 5, y0 = (pb & 31) * 2;
    const int o0 = ob * 128;
    const int w = tid >> 6, lane = tid & 63;
    const int l15 = lane & 15, kg = lane >> 4;

    // staging role: thread owns (scol, skg), one row per pass
    const int scol = (tid >> 2) & 63;
    const int skg = tid & 3;
    const int colpos = scol + 1;
    const int sslot = (skg ^ FSW(colpos)) * 8;
    const ushort* xrow_base = xb + ((size_t)(b * 64) * 64 + scol) * 512 + skg * 8;

    // A base for this wave's 32 o-rows
    const int grp = ob * 4 + w;
    const ushort* Wbase = Wf + (size_t)grp * 147456 + lane * 8;

    f32x4 acc[2][8];
    #pragma unroll
    for (int i = 0; i < 2; ++i)
        #pragma unroll
        for (int j = 0; j < 8; ++j) acc[i][j] = (f32x4){0.f, 0.f, 0.f, 0.f};

    // zero the halo pads once (colpos 0 and 65, both buffers)
    if (tid < 64) {
        int buf = tid >> 5, rem = tid & 31;
        int r = rem >> 3, side = (rem >> 2) & 1, sl = rem & 3;
        int cp = side * 65;
        *(uint4*)&sX[buf][(r * 66 + cp) * 32 + sl * 8] = make_uint4(0u, 0u, 0u, 0u);
    }

    uint4 xs[4];
    // prologue: load + stage chunk 0 into buf 0
    #pragma unroll
    for (int p = 0; p < 4; ++p) {
        int yy = y0 - 1 + p;
        xs[p] = ((unsigned)yy < 64u)
              ? *(const uint4*)(xrow_base + (size_t)yy * 32768)
              : make_uint4(0u, 0u, 0u, 0u);
    }
    #pragma unroll
    for (int p = 0; p < 4; ++p)
        *(uint4*)&sX[0][(p * 66 + colpos) * 32 + sslot] = xs[p];
    __syncthreads();

    int cur = 0;
    #pragma unroll 1
    for (int cci = 0; cci < 16; ++cci) {
        // T14: issue next chunk's global loads before compute
        if (cci < 15) {
            int cc = (cci + 1) * 32;
            #pragma unroll
            for (int p = 0; p < 4; ++p) {
                int yy = y0 - 1 + p;
                xs[p] = ((unsigned)yy < 64u)
                      ? *(const uint4*)(xrow_base + (size_t)yy * 32768 + cc)
                      : make_uint4(0u, 0u, 0u, 0u);
            }
        }
        const ushort* Wc = Wbase + (size_t)cci * 9216;
        #pragma unroll 1
        for (int g = 0; g < 3; ++g) {           // tap row (dy = g)
            uint4 a[6];
            #pragma unroll
            for (int t3 = 0; t3 < 3; ++t3)
                #pragma unroll
                for (int fm = 0; fm < 2; ++fm)
                    a[t3 * 2 + fm] = *(const uint4*)(Wc + ((g * 3 + t3) * 2 + fm) * 512);
            #pragma unroll
            for (int t3 = 0; t3 < 3; ++t3) {    // dx = t3
                #pragma unroll
                for (int fn = 0; fn < 8; ++fn) {
                    int xr = g + (fn >> 2);
                    int ci = t3 + (fn & 3) * 16 + l15;
                    bf16x8 bv = *(const bf16x8*)&sX[cur][(xr * 66 + ci) * 32 + ((kg ^ FSW(ci)) * 8)];
                    acc[0][fn] = __builtin_amdgcn_mfma_f32_16x16x32_bf16(
                        *(const bf16x8*)&a[t3 * 2 + 0], bv, acc[0][fn], 0, 0, 0);
                    acc[1][fn] = __builtin_amdgcn_mfma_f32_16x16x32_bf16(
                        *(const bf16x8*)&a[t3 * 2 + 1], bv, acc[1][fn], 0, 0, 0);
                }
            }
        }
        if (cci < 15) {
            #pragma unroll
            for (int p = 0; p < 4; ++p)
                *(uint4*)&sX[cur ^ 1][(p * 66 + colpos) * 32 + sslot] = xs[p];
            __syncthreads();
            cur ^= 1;
        }
    }

    // epilogue
    const float* sigb = sigma + b * 512;
    #pragma unroll
    for (int fm = 0; fm < 2; ++fm) {
        #pragma unroll
        for (int j = 0; j < 4; ++j) {
            int o = o0 + w * 32 + fm * 16 + kg * 4 + j;
            float sg = sigb[o];
            float bs = bias[o];
            float* op = out + ((size_t)(b * 512 + o) * 64 + y0) * 64;
            #pragma unroll
            for (int fn = 0; fn < 8; ++fn)
                op[(fn >> 2) * 64 + (fn & 3) * 16 + l15] = acc[fm][fn][j] * sg + bs;
        }
    }
}

extern "C" void kernel_launch(void* const* d_in, const int* in_sizes, int n_in,
                              void* d_out, int out_size, void* d_ws, size_t ws_size,
                              hipStream_t stream) {
    const float* x    = (const float*)d_in[0];
    const float* w    = (const float*)d_in[1];
    const float* wt   = (const float*)d_in[2];
    const float* bias = (const float*)d_in[3];
    const float* aw   = (const float*)d_in[4];
    const float* ab   = (const float*)d_in[5];
    float* out = (float*)d_out;

    // ws layout: style(16KB) | sigma(16KB) | wsq(1MB) | Wf(4.5MB) | xb(32MB)
    float* style  = (float*)d_ws;
    float* sigmap = style + 4096;
    float* wsq    = sigmap + 4096;
    ushort* Wf    = (ushort*)(wsq + 512 * 512);
    ushort* xbm   = Wf + 2359296;

    k_style <<<1024, 256, 0, stream>>>(w, aw, ab, style);
    k_wprep <<<1024, 256, 0, stream>>>(wt, Wf, wsq);
    k_premod<<< 512, 256, 0, stream>>>(x, style, xbm);
    k_sigma <<<1024, 256, 0, stream>>>(style, wsq, sigmap);
    k_conv  <<<1024, 256, 0, stream>>>(xbm, Wf, sigmap, bias, out);
}

// Round 3
// 150.533 us; speedup vs baseline: 1.2610x; 1.2610x over previous
//
#include <hip/hip_runtime.h>
#include <hip/hip_bf16.h>

typedef __attribute__((ext_vector_type(8))) short bf16x8;
typedef __attribute__((ext_vector_type(4))) float f32x4;

#define FSW(c) (((c) >> 1) & 3)

static __device__ __forceinline__ uint bf16rne(float f) {
    uint u = __float_as_uint(f);
    return (u + 0x7fffu + ((u >> 16) & 1u)) >> 16;
}

// K1: style_plus1[b][c] = 1 + affine_b[c] + dot(w[b,:], affine_w[c,:])
__global__ void k_style(const float* __restrict__ w, const float* __restrict__ aw,
                        const float* __restrict__ ab, float* __restrict__ style) {
    int idx = blockIdx.x * 4 + (threadIdx.x >> 6);
    int lane = threadIdx.x & 63;
    int b = idx >> 9, c = idx & 511;
    const float* wp = w + b * 512;
    const float* ap = aw + (size_t)c * 512;
    float s = 0.f;
    #pragma unroll
    for (int i = 0; i < 8; ++i) s += wp[lane + i * 64] * ap[lane + i * 64];
    #pragma unroll
    for (int m = 32; m; m >>= 1) s += __shfl_xor(s, m, 64);
    if (lane == 0) style[idx] = s + ab[c] + 1.0f;
}

// K2: Wf[grp16][chunk16][tap9][fm2][lane64][8] = bf16 weight in MFMA A-frag order
//     wsq[o][c] = sum_tap w^2
__global__ void k_wprep(const float* __restrict__ weight, ushort* __restrict__ Wf,
                        float* __restrict__ wsq) {
    int t = blockIdx.x * 256 + threadIdx.x;          // (o,c)
    int o = t >> 9, c = t & 511;
    int grp = o >> 5, rr = o & 31, fm = rr >> 4, l15r = rr & 15;
    int chunkid = c >> 5, kgw = (c >> 3) & 3, kk = c & 7;
    int lanew = kgw * 16 + l15r;
    const float* wp = weight + (size_t)t * 9;
    size_t G = (size_t)(grp * 16 + chunkid);
    size_t base = G * 9216 + (size_t)fm * 512 + (size_t)lanew * 8 + kk;
    float sq = 0.f;
    #pragma unroll
    for (int j = 0; j < 9; ++j) {
        float v = wp[j];
        sq += v * v;
        Wf[base + (size_t)j * 1024] = (ushort)bf16rne(v);
    }
    wsq[t] = sq;
}

// K3: sigma[b][o] = rsqrt( sum_c style^2[b,c] * wsq[o,c] + eps )
__global__ void k_sigma(const float* __restrict__ style, const float* __restrict__ wsq,
                        float* __restrict__ sigma) {
    int idx = blockIdx.x * 4 + (threadIdx.x >> 6);
    int lane = threadIdx.x & 63;
    int b = idx >> 9, o = idx & 511;
    const float* sp = style + b * 512;
    const float* qp = wsq + (size_t)o * 512;
    float s = 0.f;
    #pragma unroll
    for (int i = 0; i < 8; ++i) {
        float st = sp[lane + i * 64];
        s += st * st * qp[lane + i * 64];
    }
    #pragma unroll
    for (int m = 32; m; m >>= 1) s += __shfl_xor(s, m, 64);
    if (lane == 0) sigma[idx] = rsqrtf(s + 1e-8f);
}

// K_premod: xb[b][y][x][c] = bf16( x[b][c][y][x] * style[b][c] )   (NHWC)
__global__ void k_premod(const float* __restrict__ x, const float* __restrict__ style,
                         ushort* __restrict__ xb) {
    int bid = blockIdx.x;            // b*64 + y
    int b = bid >> 6, y = bid & 63;
    int xcol = threadIdx.x >> 2, cg = threadIdx.x & 3;
    const float* sp = style + b * 512;
    #pragma unroll 1
    for (int cb = 0; cb < 16; ++cb) {
        int c0 = cb * 32 + cg * 8;
        float v[8];
        #pragma unroll
        for (int j = 0; j < 8; ++j)
            v[j] = x[((size_t)(b * 512 + c0 + j) * 64 + y) * 64 + xcol] * sp[c0 + j];
        uint4 pk;
        pk.x = bf16rne(v[0]) | (bf16rne(v[1]) << 16);
        pk.y = bf16rne(v[2]) | (bf16rne(v[3]) << 16);
        pk.z = bf16rne(v[4]) | (bf16rne(v[5]) << 16);
        pk.w = bf16rne(v[6]) | (bf16rne(v[7]) << 16);
        *(uint4*)&xb[((size_t)(b * 64 + y) * 64 + xcol) * 512 + c0] = pk;
    }
}

// A-fragment load: 6 uint4 (3 dx x 2 fm) for tap-row G of chunk CC
#define ALOAD(ARR, G, CC) { \
    const ushort* Wc_ = Wbase + (size_t)(CC) * 9216 + (G) * 3072; \
    _Pragma("unroll") for (int q_ = 0; q_ < 6; ++q_) \
        ARR[q_] = *(const uint4*)(Wc_ + q_ * 512); }

#define MM(AV, BV, FM, FN) \
    acc[FM][FN] = __builtin_amdgcn_mfma_f32_16x16x32_bf16( \
        *(const bf16x8*)&(AV), (BV), acc[FM][FN], 0, 0, 0)

#define HGROUP(AARR, H) \
    _Pragma("unroll") for (int dx_ = 0; dx_ < 3; ++dx_) { \
      _Pragma("unroll") for (int q_ = 0; q_ < 4; ++q_) { \
        MM(AARR[dx_ * 2 + 0], bv[dx_ * 4 + q_], 0, (H) * 4 + q_); \
        MM(AARR[dx_ * 2 + 1], bv[dx_ * 4 + q_], 1, (H) * 4 + q_); \
      } }

#define ROW(R, MFMAS) { \
    bf16x8 bv[12]; \
    _Pragma("unroll") for (int dx_ = 0; dx_ < 3; ++dx_) { \
      _Pragma("unroll") for (int q_ = 0; q_ < 4; ++q_) { \
        int ci_ = dx_ + q_ * 16 + l15; \
        bv[dx_ * 4 + q_] = *(const bf16x8*)&sX[cur][((R) * 66 + ci_) * 32 + ((kg ^ FSW(ci_)) * 8)]; \
      } } \
    __builtin_amdgcn_s_setprio(1); \
    MFMAS \
    __builtin_amdgcn_s_setprio(0); }

// K4: implicit-GEMM conv. Block: 128 o x 128 px (2 rows). Wave: 32 o x 128 px.
// Input-row-phase loop shares each B-frag across both h consumers (48 ds_reads
// per chunk vs 72). A fragments (18 uint4) chunk-resident in VGPRs, reloaded
// for chunk+1 right after last use. One barrier per chunk.
__global__ __launch_bounds__(256, 2) void k_conv(
    const ushort* __restrict__ xb, const ushort* __restrict__ Wf,
    const float* __restrict__ sigma, const float* __restrict__ bias,
    float* __restrict__ out) {

    __shared__ ushort sX[2][4 * 66 * 32];   // [buf][row][col][32ch], swizzled 16B slots

    const int tid = threadIdx.x, bid = blockIdx.x;
    const int ob = bid & 3, pb = bid >> 2;
    const int b = pb >> 5, y0 = (pb & 31) * 2;
    const int o0 = ob * 128;
    const int wv = tid >> 6, lane = tid & 63;
    const int l15 = lane & 15, kg = lane >> 4;

    // x staging role: thread owns (scol, skg)
    const int scol = (tid >> 2) & 63;
    const int skg = tid & 3;
    const int colpos = scol + 1;
    const int sslot = (skg ^ FSW(colpos)) * 8;
    const ushort* xrow_base = xb + ((size_t)(b * 64) * 64 + scol) * 512 + skg * 8;

    // A base for this wave's 32 o-rows
    const int grp = ob * 4 + wv;
    const ushort* Wbase = Wf + (size_t)grp * 147456 + lane * 8;

    f32x4 acc[2][8];
    #pragma unroll
    for (int i = 0; i < 2; ++i)
        #pragma unroll
        for (int j = 0; j < 8; ++j) acc[i][j] = (f32x4){0.f, 0.f, 0.f, 0.f};

    // zero halo pads once (colpos 0 and 65, both buffers)
    if (tid < 64) {
        int buf = tid >> 5, rem = tid & 31;
        int r = rem >> 3, side = (rem >> 2) & 1, sl = rem & 3;
        int cp = side * 65;
        *(uint4*)&sX[buf][(r * 66 + cp) * 32 + sl * 8] = make_uint4(0u, 0u, 0u, 0u);
    }

    uint4 xs[4];
    #pragma unroll
    for (int p = 0; p < 4; ++p) {
        int yy = y0 - 1 + p;
        xs[p] = ((unsigned)yy < 64u)
              ? *(const uint4*)(xrow_base + (size_t)yy * 32768)
              : make_uint4(0u, 0u, 0u, 0u);
    }
    #pragma unroll
    for (int p = 0; p < 4; ++p)
        *(uint4*)&sX[0][(p * 66 + colpos) * 32 + sslot] = xs[p];

    uint4 a0[6], a1[6], a2[6];
    ALOAD(a0, 0, 0); ALOAD(a1, 1, 0); ALOAD(a2, 2, 0);
    __syncthreads();

    int cur = 0;
    #pragma unroll 1
    for (int cci = 0; cci < 16; ++cci) {
        const int ncc = (cci + 1) & 15;   // wraps at 15: harmless in-bounds reload

        // T14: issue next chunk's x loads before compute
        #pragma unroll
        for (int p = 0; p < 4; ++p) {
            int yy = y0 - 1 + p;
            xs[p] = ((unsigned)yy < 64u)
                  ? *(const uint4*)(xrow_base + (size_t)yy * 32768 + ncc * 32)
                  : make_uint4(0u, 0u, 0u, 0u);
        }

        // input-row phases; B-frag shared across both h consumers
        ROW(0, HGROUP(a0, 0))
        ROW(1, HGROUP(a0, 1) HGROUP(a1, 0))
        ALOAD(a0, 0, ncc);                 // a0 dead after row1: reload for next chunk
        ROW(2, HGROUP(a1, 1) HGROUP(a2, 0))
        ALOAD(a1, 1, ncc);
        ROW(3, HGROUP(a2, 1))
        ALOAD(a2, 2, ncc);

        // commit next chunk's x tile, single barrier
        #pragma unroll
        for (int p = 0; p < 4; ++p)
            *(uint4*)&sX[cur ^ 1][(p * 66 + colpos) * 32 + sslot] = xs[p];
        __syncthreads();
        cur ^= 1;
    }

    // epilogue: out = acc * sigma + bias
    const float* sigb = sigma + b * 512;
    #pragma unroll
    for (int fm = 0; fm < 2; ++fm) {
        #pragma unroll
        for (int j = 0; j < 4; ++j) {
            int o = o0 + wv * 32 + fm * 16 + kg * 4 + j;
            float sg = sigb[o];
            float bs = bias[o];
            float* op = out + ((size_t)(b * 512 + o) * 64 + y0) * 64;
            #pragma unroll
            for (int fn = 0; fn < 8; ++fn)
                op[(fn >> 2) * 64 + (fn & 3) * 16 + l15] = acc[fm][fn][j] * sg + bs;
        }
    }
}

extern "C" void kernel_launch(void* const* d_in, const int* in_sizes, int n_in,
                              void* d_out, int out_size, void* d_ws, size_t ws_size,
                              hipStream_t stream) {
    const float* x    = (const float*)d_in[0];
    const float* w    = (const float*)d_in[1];
    const float* wt   = (const float*)d_in[2];
    const float* bias = (const float*)d_in[3];
    const float* aw   = (const float*)d_in[4];
    const float* ab   = (const float*)d_in[5];
    float* out = (float*)d_out;

    // ws layout: style(16KB) | sigma(16KB) | wsq(1MB) | Wf(4.5MB) | xb(32MB)
    float* style  = (float*)d_ws;
    float* sigmap = style + 4096;
    float* wsq    = sigmap + 4096;
    ushort* Wf    = (ushort*)(wsq + 512 * 512);
    ushort* xbm   = Wf + 2359296;

    k_style <<<1024, 256, 0, stream>>>(w, aw, ab, style);
    k_wprep <<<1024, 256, 0, stream>>>(wt, Wf, wsq);
    k_premod<<< 512, 256, 0, stream>>>(x, style, xbm);
    k_sigma <<<1024, 256, 0, stream>>>(style, wsq, sigmap);
    k_conv  <<<1024, 256, 0, stream>>>(xbm, Wf, sigmap, bias, out);
}